// Round 1
// baseline (472.991 us; speedup 1.0000x reference)
//
#include <hip/hip_runtime.h>

#define N_NODES 65536
#define N_EDGES 1048576
#define F 128
#define F_OUT 64

// ---------------- graph preprocessing ----------------

__global__ __launch_bounds__(256) void k_init(float* deg, int* cnt, int* fill) {
    int i = blockIdx.x * 256 + threadIdx.x;
    deg[i] = 1.0f;
    cnt[i] = 0;
    fill[i] = 0;
}

__global__ __launch_bounds__(256) void k_edge_count(const int* __restrict__ dst,
                                                    const float* __restrict__ ew,
                                                    float* deg, int* cnt) {
    int e = blockIdx.x * 256 + threadIdx.x;
    int d = dst[e];
    atomicAdd(&deg[d], ew[e]);
    atomicAdd(&cnt[d], 1);
}

__global__ __launch_bounds__(256) void k_rsqrt(float* deg) {
    int i = blockIdx.x * 256 + threadIdx.x;
    deg[i] = rsqrtf(deg[i]);
}

// block-level inclusive scan -> exclusive per-element, block sums out
__global__ __launch_bounds__(256) void k_scan1(const int* __restrict__ cnt,
                                               int* __restrict__ row_ptr,
                                               int* __restrict__ bsums) {
    __shared__ int s[256];
    int t = threadIdx.x;
    int i = blockIdx.x * 256 + t;
    int v = cnt[i];
    s[t] = v;
    __syncthreads();
    for (int off = 1; off < 256; off <<= 1) {
        int tv = (t >= off) ? s[t - off] : 0;
        __syncthreads();
        s[t] += tv;
        __syncthreads();
    }
    row_ptr[i] = s[t] - v;  // exclusive
    if (t == 255) bsums[blockIdx.x] = s[255];
}

__global__ __launch_bounds__(256) void k_scan2(const int* __restrict__ bsums,
                                               int* __restrict__ boffs) {
    __shared__ int s[256];
    int t = threadIdx.x;
    int v = bsums[t];
    s[t] = v;
    __syncthreads();
    for (int off = 1; off < 256; off <<= 1) {
        int tv = (t >= off) ? s[t - off] : 0;
        __syncthreads();
        s[t] += tv;
        __syncthreads();
    }
    boffs[t] = s[t] - v;  // exclusive
}

__global__ __launch_bounds__(256) void k_scan_add(int* __restrict__ row_ptr,
                                                  const int* __restrict__ boffs) {
    int i = blockIdx.x * 256 + threadIdx.x;
    row_ptr[i] += boffs[blockIdx.x];
    if (i == 0) row_ptr[N_NODES] = N_EDGES;
}

__global__ __launch_bounds__(256) void k_scatter(const int* __restrict__ srcArr,
                                                 const int* __restrict__ dstArr,
                                                 const float* __restrict__ ew,
                                                 const float* __restrict__ dinv,
                                                 const int* __restrict__ row_ptr,
                                                 int* fill,
                                                 int* __restrict__ src_perm,
                                                 float* __restrict__ coef_perm) {
    int e = blockIdx.x * 256 + threadIdx.x;
    int s = srcArr[e];
    int d = dstArr[e];
    int pos = atomicAdd(&fill[d], 1);
    int j = row_ptr[d] + pos;
    src_perm[j] = s;
    coef_perm[j] = dinv[s] * ew[e] * dinv[d];
}

// ---------------- fp32 GEMM: C[N x BN] = X[N x 128] @ W[128 x BN] ----------------
// BM=128, BK=32, 256 threads, thread tile 8 x (BN/16)

template <int BN, bool BIAS>
__global__ __launch_bounds__(256) void k_gemm(const float* __restrict__ X,
                                              const float* __restrict__ W,
                                              const float* __restrict__ bias,
                                              float* __restrict__ C) {
    constexpr int TN = BN / 16;
    __shared__ float Xs[32][132];      // [k][row], padded
    __shared__ float Ws[32][BN + 4];   // [k][col], padded (row stride stays 16B-aligned)

    const int tid = threadIdx.x;
    const int tr = tid >> 4;   // 0..15 -> rows tr*8 .. tr*8+7
    const int tc = tid & 15;   // 0..15 -> cols tc*TN .. tc*TN+TN-1
    const long rowbase = (long)blockIdx.x * 128;

    float acc[8][TN];
#pragma unroll
    for (int i = 0; i < 8; ++i)
#pragma unroll
        for (int j = 0; j < TN; ++j) acc[i][j] = 0.f;

    for (int kk = 0; kk < 128; kk += 32) {
        // X tile: 128 rows x 32 k, transposed into Xs[k][row]
#pragma unroll
        for (int t = 0; t < 4; ++t) {
            int q = tid + t * 256;  // 0..1023 float4s
            int row = q >> 3;
            int c4 = q & 7;
            float4 v = *(const float4*)&X[(rowbase + row) * 128 + kk + c4 * 4];
            Xs[c4 * 4 + 0][row] = v.x;
            Xs[c4 * 4 + 1][row] = v.y;
            Xs[c4 * 4 + 2][row] = v.z;
            Xs[c4 * 4 + 3][row] = v.w;
        }
        // W tile: 32 k-rows x BN cols, direct copy
#pragma unroll
        for (int t = 0; t < (32 * BN / 4) / 256; ++t) {
            int q = tid + t * 256;
            int row = q / (BN / 4);
            int c4 = q % (BN / 4);
            *(float4*)&Ws[row][c4 * 4] = *(const float4*)&W[(kk + row) * BN + c4 * 4];
        }
        __syncthreads();

#pragma unroll 8
        for (int k = 0; k < 32; ++k) {
            float a[8], b[TN];
            *(float4*)&a[0] = *(const float4*)&Xs[k][tr * 8];
            *(float4*)&a[4] = *(const float4*)&Xs[k][tr * 8 + 4];
#pragma unroll
            for (int j = 0; j < TN; j += 4)
                *(float4*)&b[j] = *(const float4*)&Ws[k][tc * TN + j];
#pragma unroll
            for (int i = 0; i < 8; ++i)
#pragma unroll
                for (int j = 0; j < TN; ++j)
                    acc[i][j] = fmaf(a[i], b[j], acc[i][j]);
        }
        __syncthreads();
    }

#pragma unroll
    for (int i = 0; i < 8; ++i) {
        long row = rowbase + tr * 8 + i;
#pragma unroll
        for (int j = 0; j < TN; j += 4) {
            float4 v;
            v.x = acc[i][j];
            v.y = acc[i][j + 1];
            v.z = acc[i][j + 2];
            v.w = acc[i][j + 3];
            if (BIAS) {
                v.x += bias[tc * TN + j];
                v.y += bias[tc * TN + j + 1];
                v.z += bias[tc * TN + j + 2];
                v.w += bias[tc * TN + j + 3];
            }
            *(float4*)&C[row * BN + tc * TN + j] = v;
        }
    }
}

// ---------------- CSR gather aggregation ----------------
// one wave per dst node; 64 lanes x float2 = 128 features

__global__ __launch_bounds__(256) void k_aggregate(const float* __restrict__ hlin,
                                                   const int* __restrict__ row_ptr,
                                                   const int* __restrict__ src_perm,
                                                   const float* __restrict__ coef,
                                                   const float* __restrict__ dinv,
                                                   const float* __restrict__ bias,
                                                   float* __restrict__ out,
                                                   int do_relu) {
    int wave = threadIdx.x >> 6;
    int lane = threadIdx.x & 63;
    int n = (blockIdx.x << 2) + wave;

    float di = dinv[n];
    float sc = di * di;

    float2 h0 = ((const float2*)hlin)[(size_t)n * 64 + lane];
    float2 acc;
    acc.x = h0.x * sc;
    acc.y = h0.y * sc;

    int beg = row_ptr[n];
    int end = row_ptr[n + 1];
    for (int j = beg; j < end; ++j) {
        int s = src_perm[j];
        float c = coef[j];
        float2 hs = ((const float2*)hlin)[(size_t)s * 64 + lane];
        acc.x = fmaf(c, hs.x, acc.x);
        acc.y = fmaf(c, hs.y, acc.y);
    }

    float2 bb = ((const float2*)bias)[lane];
    acc.x += bb.x;
    acc.y += bb.y;
    if (do_relu) {
        acc.x = fmaxf(acc.x, 0.f);
        acc.y = fmaxf(acc.y, 0.f);
    }
    ((float2*)out)[(size_t)n * 64 + lane] = acc;
}

// ---------------- launch ----------------

extern "C" void kernel_launch(void* const* d_in, const int* in_sizes, int n_in,
                              void* d_out, int out_size, void* d_ws, size_t ws_size,
                              hipStream_t stream) {
    const float* x   = (const float*)d_in[0];
    const int*   ei  = (const int*)d_in[1];
    const float* ew  = (const float*)d_in[2];
    const float* W1  = (const float*)d_in[4];
    const float* b1  = (const float*)d_in[5];
    const float* W2  = (const float*)d_in[6];
    const float* b2  = (const float*)d_in[7];
    const float* fcW = (const float*)d_in[8];
    const float* fcb = (const float*)d_in[9];
    float* out = (float*)d_out;

    const int* srcArr = ei;             // edge_index[0]
    const int* dstArr = ei + N_EDGES;   // edge_index[1]

    char* w = (char*)d_ws;
    float* deg = (float*)w;            w += (size_t)N_NODES * 4;   // becomes dinv
    int* cnt = (int*)w;                w += (size_t)N_NODES * 4;
    int* fill = (int*)w;               w += (size_t)N_NODES * 4;
    int* row_ptr = (int*)w;            w += (size_t)(N_NODES + 64) * 4;
    int* bsums = (int*)w;              w += 256 * 4;
    int* boffs = (int*)w;              w += 256 * 4;
    int* src_perm = (int*)w;           w += (size_t)N_EDGES * 4;
    float* coef = (float*)w;           w += (size_t)N_EDGES * 4;
    float* bufA = (float*)w;           w += (size_t)N_NODES * F * 4;
    float* bufB = (float*)w;           w += (size_t)N_NODES * F * 4;

    k_init<<<N_NODES / 256, 256, 0, stream>>>(deg, cnt, fill);
    k_edge_count<<<N_EDGES / 256, 256, 0, stream>>>(dstArr, ew, deg, cnt);
    k_rsqrt<<<N_NODES / 256, 256, 0, stream>>>(deg);
    k_scan1<<<256, 256, 0, stream>>>(cnt, row_ptr, bsums);
    k_scan2<<<1, 256, 0, stream>>>(bsums, boffs);
    k_scan_add<<<256, 256, 0, stream>>>(row_ptr, boffs);
    k_scatter<<<N_EDGES / 256, 256, 0, stream>>>(srcArr, dstArr, ew, deg, row_ptr, fill,
                                                 src_perm, coef);

    // layer 1
    k_gemm<128, false><<<512, 256, 0, stream>>>(x, W1, nullptr, bufA);
    k_aggregate<<<N_NODES / 4, 256, 0, stream>>>(bufA, row_ptr, src_perm, coef, deg, b1,
                                                 bufB, 1);
    // layer 2
    k_gemm<128, false><<<512, 256, 0, stream>>>(bufB, W2, nullptr, bufA);
    k_aggregate<<<N_NODES / 4, 256, 0, stream>>>(bufA, row_ptr, src_perm, coef, deg, b2,
                                                 bufB, 1);
    // FC
    k_gemm<64, true><<<512, 256, 0, stream>>>(bufB, fcW, fcb, out);
}

// Round 2
// 397.822 us; speedup vs baseline: 1.1890x; 1.1890x over previous
//
#include <hip/hip_runtime.h>

#define N_NODES 65536
#define N_EDGES 1048576
#define F 128
#define F_OUT 64

// ---------------- graph preprocessing ----------------

__global__ __launch_bounds__(256) void k_init(float* deg, int* cnt, int* fill) {
    int i = blockIdx.x * 256 + threadIdx.x;
    deg[i] = 1.0f;
    cnt[i] = 0;
    fill[i] = 0;
}

__global__ __launch_bounds__(256) void k_edge_count(const int* __restrict__ dst,
                                                    const float* __restrict__ ew,
                                                    float* deg, int* cnt) {
    int e = blockIdx.x * 256 + threadIdx.x;
    int d = dst[e];
    atomicAdd(&deg[d], ew[e]);
    atomicAdd(&cnt[d], 1);
}

__global__ __launch_bounds__(256) void k_rsqrt(float* deg) {
    int i = blockIdx.x * 256 + threadIdx.x;
    deg[i] = rsqrtf(deg[i]);
}

// block-level inclusive scan -> exclusive per-element, block sums out
__global__ __launch_bounds__(256) void k_scan1(const int* __restrict__ cnt,
                                               int* __restrict__ row_ptr,
                                               int* __restrict__ bsums) {
    __shared__ int s[256];
    int t = threadIdx.x;
    int i = blockIdx.x * 256 + t;
    int v = cnt[i];
    s[t] = v;
    __syncthreads();
    for (int off = 1; off < 256; off <<= 1) {
        int tv = (t >= off) ? s[t - off] : 0;
        __syncthreads();
        s[t] += tv;
        __syncthreads();
    }
    row_ptr[i] = s[t] - v;  // exclusive
    if (t == 255) bsums[blockIdx.x] = s[255];
}

__global__ __launch_bounds__(256) void k_scan2(const int* __restrict__ bsums,
                                               int* __restrict__ boffs) {
    __shared__ int s[256];
    int t = threadIdx.x;
    int v = bsums[t];
    s[t] = v;
    __syncthreads();
    for (int off = 1; off < 256; off <<= 1) {
        int tv = (t >= off) ? s[t - off] : 0;
        __syncthreads();
        s[t] += tv;
        __syncthreads();
    }
    boffs[t] = s[t] - v;  // exclusive
}

__global__ __launch_bounds__(256) void k_scan_add(int* __restrict__ row_ptr,
                                                  const int* __restrict__ boffs) {
    int i = blockIdx.x * 256 + threadIdx.x;
    row_ptr[i] += boffs[blockIdx.x];
    if (i == 0) row_ptr[N_NODES] = N_EDGES;
}

__global__ __launch_bounds__(256) void k_scatter(const int* __restrict__ srcArr,
                                                 const int* __restrict__ dstArr,
                                                 const float* __restrict__ ew,
                                                 const float* __restrict__ dinv,
                                                 const int* __restrict__ row_ptr,
                                                 int* fill,
                                                 int* __restrict__ src_perm,
                                                 float* __restrict__ coef_perm) {
    int e = blockIdx.x * 256 + threadIdx.x;
    int s = srcArr[e];
    int d = dstArr[e];
    int pos = atomicAdd(&fill[d], 1);
    int j = row_ptr[d] + pos;
    src_perm[j] = s;
    coef_perm[j] = dinv[s] * ew[e] * dinv[d];
}

// ---------------- fp32 GEMM: C[N x BN] = X[N x 128] @ W[128 x BN] ----------------
// BM=128, BK=32, 256 threads, thread tile 8 x (BN/16)

template <int BN, bool BIAS>
__global__ __launch_bounds__(256) void k_gemm(const float* __restrict__ X,
                                              const float* __restrict__ W,
                                              const float* __restrict__ bias,
                                              float* __restrict__ C) {
    constexpr int TN = BN / 16;
    __shared__ float Xs[32][132];      // [k][row], padded
    __shared__ float Ws[32][BN + 4];   // [k][col], padded

    const int tid = threadIdx.x;
    const int tr = tid >> 4;   // 0..15 -> rows tr*8 .. tr*8+7
    const int tc = tid & 15;   // 0..15 -> cols tc*TN .. tc*TN+TN-1
    const long rowbase = (long)blockIdx.x * 128;

    float acc[8][TN];
#pragma unroll
    for (int i = 0; i < 8; ++i)
#pragma unroll
        for (int j = 0; j < TN; ++j) acc[i][j] = 0.f;

    for (int kk = 0; kk < 128; kk += 32) {
#pragma unroll
        for (int t = 0; t < 4; ++t) {
            int q = tid + t * 256;  // 0..1023 float4s
            int row = q >> 3;
            int c4 = q & 7;
            float4 v = *(const float4*)&X[(rowbase + row) * 128 + kk + c4 * 4];
            Xs[c4 * 4 + 0][row] = v.x;
            Xs[c4 * 4 + 1][row] = v.y;
            Xs[c4 * 4 + 2][row] = v.z;
            Xs[c4 * 4 + 3][row] = v.w;
        }
#pragma unroll
        for (int t = 0; t < (32 * BN / 4) / 256; ++t) {
            int q = tid + t * 256;
            int row = q / (BN / 4);
            int c4 = q % (BN / 4);
            *(float4*)&Ws[row][c4 * 4] = *(const float4*)&W[(kk + row) * BN + c4 * 4];
        }
        __syncthreads();

#pragma unroll 8
        for (int k = 0; k < 32; ++k) {
            float a[8], b[TN];
            *(float4*)&a[0] = *(const float4*)&Xs[k][tr * 8];
            *(float4*)&a[4] = *(const float4*)&Xs[k][tr * 8 + 4];
#pragma unroll
            for (int j = 0; j < TN; j += 4)
                *(float4*)&b[j] = *(const float4*)&Ws[k][tc * TN + j];
#pragma unroll
            for (int i = 0; i < 8; ++i)
#pragma unroll
                for (int j = 0; j < TN; ++j)
                    acc[i][j] = fmaf(a[i], b[j], acc[i][j]);
        }
        __syncthreads();
    }

#pragma unroll
    for (int i = 0; i < 8; ++i) {
        long row = rowbase + tr * 8 + i;
#pragma unroll
        for (int j = 0; j < TN; j += 4) {
            float4 v;
            v.x = acc[i][j];
            v.y = acc[i][j + 1];
            v.z = acc[i][j + 2];
            v.w = acc[i][j + 3];
            if (BIAS) {
                v.x += bias[tc * TN + j];
                v.y += bias[tc * TN + j + 1];
                v.z += bias[tc * TN + j + 2];
                v.w += bias[tc * TN + j + 3];
            }
            *(float4*)&C[row * BN + tc * TN + j] = v;
        }
    }
}

// ---------------- CSR gather aggregation ----------------
// one wave per dst node; 64 lanes x float2 = 128 features.
// Batch-load (src,coef) for up to 64 edges with one coalesced load, then
// shfl-broadcast and issue 8 independent row-gathers per iteration into 8
// independent accumulators (MLP=8). Tail padded with coef=0 -> gathers row 0
// (L2-hot, harmless).

__global__ __launch_bounds__(256) void k_aggregate(const float* __restrict__ hlin,
                                                   const int* __restrict__ row_ptr,
                                                   const int* __restrict__ src_perm,
                                                   const float* __restrict__ coef,
                                                   const float* __restrict__ dinv,
                                                   const float* __restrict__ bias,
                                                   float* __restrict__ out,
                                                   int do_relu) {
    int wave = threadIdx.x >> 6;
    int lane = threadIdx.x & 63;
    int n = (blockIdx.x << 2) + wave;

    float di = dinv[n];
    float sc = di * di;

    float2 h0 = ((const float2*)hlin)[(size_t)n * 64 + lane];
    float2 a0, a1, a2, a3, a4, a5, a6, a7;
    a0.x = h0.x * sc; a0.y = h0.y * sc;
    a1 = a2 = a3 = a4 = a5 = a6 = a7 = make_float2(0.f, 0.f);

    int beg = row_ptr[n];
    int end = row_ptr[n + 1];
    for (int jb = beg; jb < end; jb += 64) {
        int nload = end - jb;
        if (nload > 64) nload = 64;
        int s = 0;
        float c = 0.f;
        if (lane < nload) {
            s = src_perm[jb + lane];
            c = coef[jb + lane];
        }
        for (int q = 0; q < nload; q += 8) {
            int s0 = __shfl(s, q + 0), s1 = __shfl(s, q + 1);
            int s2 = __shfl(s, q + 2), s3 = __shfl(s, q + 3);
            int s4 = __shfl(s, q + 4), s5 = __shfl(s, q + 5);
            int s6 = __shfl(s, q + 6), s7 = __shfl(s, q + 7);
            float c0 = __shfl(c, q + 0), c1 = __shfl(c, q + 1);
            float c2 = __shfl(c, q + 2), c3 = __shfl(c, q + 3);
            float c4 = __shfl(c, q + 4), c5 = __shfl(c, q + 5);
            float c6 = __shfl(c, q + 6), c7 = __shfl(c, q + 7);
            float2 g0 = ((const float2*)hlin)[(size_t)s0 * 64 + lane];
            float2 g1 = ((const float2*)hlin)[(size_t)s1 * 64 + lane];
            float2 g2 = ((const float2*)hlin)[(size_t)s2 * 64 + lane];
            float2 g3 = ((const float2*)hlin)[(size_t)s3 * 64 + lane];
            float2 g4 = ((const float2*)hlin)[(size_t)s4 * 64 + lane];
            float2 g5 = ((const float2*)hlin)[(size_t)s5 * 64 + lane];
            float2 g6 = ((const float2*)hlin)[(size_t)s6 * 64 + lane];
            float2 g7 = ((const float2*)hlin)[(size_t)s7 * 64 + lane];
            a0.x = fmaf(c0, g0.x, a0.x); a0.y = fmaf(c0, g0.y, a0.y);
            a1.x = fmaf(c1, g1.x, a1.x); a1.y = fmaf(c1, g1.y, a1.y);
            a2.x = fmaf(c2, g2.x, a2.x); a2.y = fmaf(c2, g2.y, a2.y);
            a3.x = fmaf(c3, g3.x, a3.x); a3.y = fmaf(c3, g3.y, a3.y);
            a4.x = fmaf(c4, g4.x, a4.x); a4.y = fmaf(c4, g4.y, a4.y);
            a5.x = fmaf(c5, g5.x, a5.x); a5.y = fmaf(c5, g5.y, a5.y);
            a6.x = fmaf(c6, g6.x, a6.x); a6.y = fmaf(c6, g6.y, a6.y);
            a7.x = fmaf(c7, g7.x, a7.x); a7.y = fmaf(c7, g7.y, a7.y);
        }
    }

    float2 acc;
    acc.x = ((a0.x + a1.x) + (a2.x + a3.x)) + ((a4.x + a5.x) + (a6.x + a7.x));
    acc.y = ((a0.y + a1.y) + (a2.y + a3.y)) + ((a4.y + a5.y) + (a6.y + a7.y));

    float2 bb = ((const float2*)bias)[lane];
    acc.x += bb.x;
    acc.y += bb.y;
    if (do_relu) {
        acc.x = fmaxf(acc.x, 0.f);
        acc.y = fmaxf(acc.y, 0.f);
    }
    ((float2*)out)[(size_t)n * 64 + lane] = acc;
}

// ---------------- launch ----------------

extern "C" void kernel_launch(void* const* d_in, const int* in_sizes, int n_in,
                              void* d_out, int out_size, void* d_ws, size_t ws_size,
                              hipStream_t stream) {
    const float* x   = (const float*)d_in[0];
    const int*   ei  = (const int*)d_in[1];
    const float* ew  = (const float*)d_in[2];
    const float* W1  = (const float*)d_in[4];
    const float* b1  = (const float*)d_in[5];
    const float* W2  = (const float*)d_in[6];
    const float* b2  = (const float*)d_in[7];
    const float* fcW = (const float*)d_in[8];
    const float* fcb = (const float*)d_in[9];
    float* out = (float*)d_out;

    const int* srcArr = ei;             // edge_index[0]
    const int* dstArr = ei + N_EDGES;   // edge_index[1]

    char* w = (char*)d_ws;
    float* deg = (float*)w;            w += (size_t)N_NODES * 4;   // becomes dinv
    int* cnt = (int*)w;                w += (size_t)N_NODES * 4;
    int* fill = (int*)w;               w += (size_t)N_NODES * 4;
    int* row_ptr = (int*)w;            w += (size_t)(N_NODES + 64) * 4;
    int* bsums = (int*)w;              w += 256 * 4;
    int* boffs = (int*)w;              w += 256 * 4;
    int* src_perm = (int*)w;           w += (size_t)N_EDGES * 4;
    float* coef = (float*)w;           w += (size_t)N_EDGES * 4;
    float* bufA = (float*)w;           w += (size_t)N_NODES * F * 4;
    float* bufB = (float*)w;           w += (size_t)N_NODES * F * 4;

    k_init<<<N_NODES / 256, 256, 0, stream>>>(deg, cnt, fill);
    k_edge_count<<<N_EDGES / 256, 256, 0, stream>>>(dstArr, ew, deg, cnt);
    k_rsqrt<<<N_NODES / 256, 256, 0, stream>>>(deg);
    k_scan1<<<256, 256, 0, stream>>>(cnt, row_ptr, bsums);
    k_scan2<<<1, 256, 0, stream>>>(bsums, boffs);
    k_scan_add<<<256, 256, 0, stream>>>(row_ptr, boffs);
    k_scatter<<<N_EDGES / 256, 256, 0, stream>>>(srcArr, dstArr, ew, deg, row_ptr, fill,
                                                 src_perm, coef);

    // layer 1
    k_gemm<128, false><<<512, 256, 0, stream>>>(x, W1, nullptr, bufA);
    k_aggregate<<<N_NODES / 4, 256, 0, stream>>>(bufA, row_ptr, src_perm, coef, deg, b1,
                                                 bufB, 1);
    // layer 2
    k_gemm<128, false><<<512, 256, 0, stream>>>(bufB, W2, nullptr, bufA);
    k_aggregate<<<N_NODES / 4, 256, 0, stream>>>(bufA, row_ptr, src_perm, coef, deg, b2,
                                                 bufB, 1);
    // FC
    k_gemm<64, true><<<512, 256, 0, stream>>>(bufB, fcW, fcb, out);
}

// Round 3
// 335.687 us; speedup vs baseline: 1.4090x; 1.1851x over previous
//
#include <hip/hip_runtime.h>

#define N_NODES 65536
#define N_EDGES 1048576
#define F 128
#define F_OUT 64

// ---------------- graph preprocessing ----------------
// packed[d]: high 24 bits = in-edge count, low 40 bits = sum(ew) in fixed
// point with 30 fraction bits (max per-node sum << 1024, so no carry into
// the count field). One 64-bit fetch-add per edge replaces 3 atomics:
// deg-add, cnt-add, and the CSR fill fetch-add (rank = old>>40).

__global__ __launch_bounds__(256) void k_zero(unsigned long long* packed) {
    packed[blockIdx.x * 256 + threadIdx.x] = 0ULL;
}

__global__ __launch_bounds__(256) void k_hist(const int* __restrict__ dst,
                                              const float* __restrict__ ew,
                                              unsigned long long* __restrict__ packed,
                                              unsigned short* __restrict__ rank) {
    int e = blockIdx.x * 256 + threadIdx.x;
    int d = dst[e];
    float w = ew[e];
    unsigned long long fx = (unsigned long long)(w * 1073741824.0f);  // 2^30
    unsigned long long old = atomicAdd(&packed[d], (1ULL << 40) | fx);
    rank[e] = (unsigned short)(old >> 40);
}

__global__ __launch_bounds__(256) void k_dinv(const unsigned long long* __restrict__ packed,
                                              float* __restrict__ dinv) {
    int i = blockIdx.x * 256 + threadIdx.x;
    unsigned long long p = packed[i];
    float deg = 1.0f + (float)(p & ((1ULL << 40) - 1)) * (1.0f / 1073741824.0f);
    dinv[i] = rsqrtf(deg);
}

// block-level inclusive scan -> exclusive per-element, block sums out
__global__ __launch_bounds__(256) void k_scan1(const unsigned long long* __restrict__ packed,
                                               int* __restrict__ row_ptr,
                                               int* __restrict__ bsums) {
    __shared__ int s[256];
    int t = threadIdx.x;
    int i = blockIdx.x * 256 + t;
    int v = (int)(packed[i] >> 40);
    s[t] = v;
    __syncthreads();
    for (int off = 1; off < 256; off <<= 1) {
        int tv = (t >= off) ? s[t - off] : 0;
        __syncthreads();
        s[t] += tv;
        __syncthreads();
    }
    row_ptr[i] = s[t] - v;  // exclusive
    if (t == 255) bsums[blockIdx.x] = s[255];
}

__global__ __launch_bounds__(256) void k_scan2(const int* __restrict__ bsums,
                                               int* __restrict__ boffs) {
    __shared__ int s[256];
    int t = threadIdx.x;
    int v = bsums[t];
    s[t] = v;
    __syncthreads();
    for (int off = 1; off < 256; off <<= 1) {
        int tv = (t >= off) ? s[t - off] : 0;
        __syncthreads();
        s[t] += tv;
        __syncthreads();
    }
    boffs[t] = s[t] - v;  // exclusive
}

__global__ __launch_bounds__(256) void k_scan_add(int* __restrict__ row_ptr,
                                                  const int* __restrict__ boffs) {
    int i = blockIdx.x * 256 + threadIdx.x;
    row_ptr[i] += boffs[blockIdx.x];
    if (i == 0) row_ptr[N_NODES] = N_EDGES;
}

// atomic-free scatter: position comes from rank captured in k_hist
__global__ __launch_bounds__(256) void k_scatter(const int* __restrict__ srcArr,
                                                 const int* __restrict__ dstArr,
                                                 const float* __restrict__ ew,
                                                 const float* __restrict__ dinv,
                                                 const int* __restrict__ row_ptr,
                                                 const unsigned short* __restrict__ rank,
                                                 int* __restrict__ src_perm,
                                                 float* __restrict__ coef_perm) {
    int e = blockIdx.x * 256 + threadIdx.x;
    int s = srcArr[e];
    int d = dstArr[e];
    int j = row_ptr[d] + (int)rank[e];
    src_perm[j] = s;
    coef_perm[j] = dinv[s] * ew[e] * dinv[d];
}

// ---------------- fp32 GEMM: C[N x BN] = X[N x 128] @ W[128 x BN] ----------------
// BM=128, BK=32, 256 threads, thread tile 8 x (BN/16)

template <int BN, bool BIAS>
__global__ __launch_bounds__(256) void k_gemm(const float* __restrict__ X,
                                              const float* __restrict__ W,
                                              const float* __restrict__ bias,
                                              float* __restrict__ C) {
    constexpr int TN = BN / 16;
    __shared__ float Xs[32][132];      // [k][row], padded
    __shared__ float Ws[32][BN + 4];   // [k][col], padded

    const int tid = threadIdx.x;
    const int tr = tid >> 4;   // 0..15 -> rows tr*8 .. tr*8+7
    const int tc = tid & 15;   // 0..15 -> cols tc*TN .. tc*TN+TN-1
    const long rowbase = (long)blockIdx.x * 128;

    float acc[8][TN];
#pragma unroll
    for (int i = 0; i < 8; ++i)
#pragma unroll
        for (int j = 0; j < TN; ++j) acc[i][j] = 0.f;

    for (int kk = 0; kk < 128; kk += 32) {
#pragma unroll
        for (int t = 0; t < 4; ++t) {
            int q = tid + t * 256;  // 0..1023 float4s
            int row = q >> 3;
            int c4 = q & 7;
            float4 v = *(const float4*)&X[(rowbase + row) * 128 + kk + c4 * 4];
            Xs[c4 * 4 + 0][row] = v.x;
            Xs[c4 * 4 + 1][row] = v.y;
            Xs[c4 * 4 + 2][row] = v.z;
            Xs[c4 * 4 + 3][row] = v.w;
        }
#pragma unroll
        for (int t = 0; t < (32 * BN / 4) / 256; ++t) {
            int q = tid + t * 256;
            int row = q / (BN / 4);
            int c4 = q % (BN / 4);
            *(float4*)&Ws[row][c4 * 4] = *(const float4*)&W[(kk + row) * BN + c4 * 4];
        }
        __syncthreads();

#pragma unroll 8
        for (int k = 0; k < 32; ++k) {
            float a[8], b[TN];
            *(float4*)&a[0] = *(const float4*)&Xs[k][tr * 8];
            *(float4*)&a[4] = *(const float4*)&Xs[k][tr * 8 + 4];
#pragma unroll
            for (int j = 0; j < TN; j += 4)
                *(float4*)&b[j] = *(const float4*)&Ws[k][tc * TN + j];
#pragma unroll
            for (int i = 0; i < 8; ++i)
#pragma unroll
                for (int j = 0; j < TN; ++j)
                    acc[i][j] = fmaf(a[i], b[j], acc[i][j]);
        }
        __syncthreads();
    }

#pragma unroll
    for (int i = 0; i < 8; ++i) {
        long row = rowbase + tr * 8 + i;
#pragma unroll
        for (int j = 0; j < TN; j += 4) {
            float4 v;
            v.x = acc[i][j];
            v.y = acc[i][j + 1];
            v.z = acc[i][j + 2];
            v.w = acc[i][j + 3];
            if (BIAS) {
                v.x += bias[tc * TN + j];
                v.y += bias[tc * TN + j + 1];
                v.z += bias[tc * TN + j + 2];
                v.w += bias[tc * TN + j + 3];
            }
            *(float4*)&C[row * BN + tc * TN + j] = v;
        }
    }
}

// ---------------- CSR gather aggregation ----------------
// one wave per dst node; 64 lanes x float2 = 128 features.
// Batch-load (src,coef) for up to 64 edges with one coalesced load, then
// shfl-broadcast and issue 8 independent row-gathers per iteration into 8
// independent accumulators (MLP=8). Tail padded with coef=0 -> gathers row 0
// (L2-hot, harmless).

__global__ __launch_bounds__(256) void k_aggregate(const float* __restrict__ hlin,
                                                   const int* __restrict__ row_ptr,
                                                   const int* __restrict__ src_perm,
                                                   const float* __restrict__ coef,
                                                   const float* __restrict__ dinv,
                                                   const float* __restrict__ bias,
                                                   float* __restrict__ out,
                                                   int do_relu) {
    int wave = threadIdx.x >> 6;
    int lane = threadIdx.x & 63;
    int n = (blockIdx.x << 2) + wave;

    float di = dinv[n];
    float sc = di * di;

    float2 h0 = ((const float2*)hlin)[(size_t)n * 64 + lane];
    float2 a0, a1, a2, a3, a4, a5, a6, a7;
    a0.x = h0.x * sc; a0.y = h0.y * sc;
    a1 = a2 = a3 = a4 = a5 = a6 = a7 = make_float2(0.f, 0.f);

    int beg = row_ptr[n];
    int end = row_ptr[n + 1];
    for (int jb = beg; jb < end; jb += 64) {
        int nload = end - jb;
        if (nload > 64) nload = 64;
        int s = 0;
        float c = 0.f;
        if (lane < nload) {
            s = src_perm[jb + lane];
            c = coef[jb + lane];
        }
        for (int q = 0; q < nload; q += 8) {
            int s0 = __shfl(s, q + 0), s1 = __shfl(s, q + 1);
            int s2 = __shfl(s, q + 2), s3 = __shfl(s, q + 3);
            int s4 = __shfl(s, q + 4), s5 = __shfl(s, q + 5);
            int s6 = __shfl(s, q + 6), s7 = __shfl(s, q + 7);
            float c0 = __shfl(c, q + 0), c1 = __shfl(c, q + 1);
            float c2 = __shfl(c, q + 2), c3 = __shfl(c, q + 3);
            float c4 = __shfl(c, q + 4), c5 = __shfl(c, q + 5);
            float c6 = __shfl(c, q + 6), c7 = __shfl(c, q + 7);
            float2 g0 = ((const float2*)hlin)[(size_t)s0 * 64 + lane];
            float2 g1 = ((const float2*)hlin)[(size_t)s1 * 64 + lane];
            float2 g2 = ((const float2*)hlin)[(size_t)s2 * 64 + lane];
            float2 g3 = ((const float2*)hlin)[(size_t)s3 * 64 + lane];
            float2 g4 = ((const float2*)hlin)[(size_t)s4 * 64 + lane];
            float2 g5 = ((const float2*)hlin)[(size_t)s5 * 64 + lane];
            float2 g6 = ((const float2*)hlin)[(size_t)s6 * 64 + lane];
            float2 g7 = ((const float2*)hlin)[(size_t)s7 * 64 + lane];
            a0.x = fmaf(c0, g0.x, a0.x); a0.y = fmaf(c0, g0.y, a0.y);
            a1.x = fmaf(c1, g1.x, a1.x); a1.y = fmaf(c1, g1.y, a1.y);
            a2.x = fmaf(c2, g2.x, a2.x); a2.y = fmaf(c2, g2.y, a2.y);
            a3.x = fmaf(c3, g3.x, a3.x); a3.y = fmaf(c3, g3.y, a3.y);
            a4.x = fmaf(c4, g4.x, a4.x); a4.y = fmaf(c4, g4.y, a4.y);
            a5.x = fmaf(c5, g5.x, a5.x); a5.y = fmaf(c5, g5.y, a5.y);
            a6.x = fmaf(c6, g6.x, a6.x); a6.y = fmaf(c6, g6.y, a6.y);
            a7.x = fmaf(c7, g7.x, a7.x); a7.y = fmaf(c7, g7.y, a7.y);
        }
    }

    float2 acc;
    acc.x = ((a0.x + a1.x) + (a2.x + a3.x)) + ((a4.x + a5.x) + (a6.x + a7.x));
    acc.y = ((a0.y + a1.y) + (a2.y + a3.y)) + ((a4.y + a5.y) + (a6.y + a7.y));

    float2 bb = ((const float2*)bias)[lane];
    acc.x += bb.x;
    acc.y += bb.y;
    if (do_relu) {
        acc.x = fmaxf(acc.x, 0.f);
        acc.y = fmaxf(acc.y, 0.f);
    }
    ((float2*)out)[(size_t)n * 64 + lane] = acc;
}

// ---------------- launch ----------------

extern "C" void kernel_launch(void* const* d_in, const int* in_sizes, int n_in,
                              void* d_out, int out_size, void* d_ws, size_t ws_size,
                              hipStream_t stream) {
    const float* x   = (const float*)d_in[0];
    const int*   ei  = (const int*)d_in[1];
    const float* ew  = (const float*)d_in[2];
    const float* W1  = (const float*)d_in[4];
    const float* b1  = (const float*)d_in[5];
    const float* W2  = (const float*)d_in[6];
    const float* b2  = (const float*)d_in[7];
    const float* fcW = (const float*)d_in[8];
    const float* fcb = (const float*)d_in[9];
    float* out = (float*)d_out;

    const int* srcArr = ei;             // edge_index[0]
    const int* dstArr = ei + N_EDGES;   // edge_index[1]

    char* w = (char*)d_ws;
    unsigned long long* packed = (unsigned long long*)w; w += (size_t)N_NODES * 8;
    float* dinv = (float*)w;           w += (size_t)N_NODES * 4;
    unsigned short* rank = (unsigned short*)w; w += (size_t)N_EDGES * 2;
    int* row_ptr = (int*)w;            w += (size_t)(N_NODES + 64) * 4;
    int* bsums = (int*)w;              w += 256 * 4;
    int* boffs = (int*)w;              w += 256 * 4;
    int* src_perm = (int*)w;           w += (size_t)N_EDGES * 4;
    float* coef = (float*)w;           w += (size_t)N_EDGES * 4;
    float* bufA = (float*)w;           w += (size_t)N_NODES * F * 4;
    float* bufB = (float*)w;           w += (size_t)N_NODES * F * 4;

    k_zero<<<N_NODES / 256, 256, 0, stream>>>(packed);
    k_hist<<<N_EDGES / 256, 256, 0, stream>>>(dstArr, ew, packed, rank);
    k_dinv<<<N_NODES / 256, 256, 0, stream>>>(packed, dinv);
    k_scan1<<<256, 256, 0, stream>>>(packed, row_ptr, bsums);
    k_scan2<<<1, 256, 0, stream>>>(bsums, boffs);
    k_scan_add<<<256, 256, 0, stream>>>(row_ptr, boffs);
    k_scatter<<<N_EDGES / 256, 256, 0, stream>>>(srcArr, dstArr, ew, dinv, row_ptr, rank,
                                                 src_perm, coef);

    // layer 1
    k_gemm<128, false><<<512, 256, 0, stream>>>(x, W1, nullptr, bufA);
    k_aggregate<<<N_NODES / 4, 256, 0, stream>>>(bufA, row_ptr, src_perm, coef, dinv, b1,
                                                 bufB, 1);
    // layer 2
    k_gemm<128, false><<<512, 256, 0, stream>>>(bufB, W2, nullptr, bufA);
    k_aggregate<<<N_NODES / 4, 256, 0, stream>>>(bufA, row_ptr, src_perm, coef, dinv, b2,
                                                 bufB, 1);
    // FC
    k_gemm<64, true><<<512, 256, 0, stream>>>(bufB, fcW, fcb, out);
}

// Round 4
// 257.180 us; speedup vs baseline: 1.8391x; 1.3053x over previous
//
#include <hip/hip_runtime.h>
#include <hip/hip_fp16.h>

#define N_NODES 65536
#define N_EDGES 1048576
#define F 128
#define F_OUT 64

// ---------------- graph preprocessing ----------------
// packed[d]: high 24 bits = in-edge count, low 40 bits = sum(ew) in fixed
// point with 30 fraction bits. One 64-bit fetch-add per edge gives deg-sum,
// count, and the edge's rank within its dst bucket (old>>40).

__global__ __launch_bounds__(256) void k_zero(unsigned long long* packed) {
    packed[blockIdx.x * 256 + threadIdx.x] = 0ULL;
}

__global__ __launch_bounds__(256) void k_hist(const int* __restrict__ dst,
                                              const float* __restrict__ ew,
                                              unsigned long long* __restrict__ packed,
                                              unsigned short* __restrict__ rank) {
    int e = blockIdx.x * 256 + threadIdx.x;
    int d = dst[e];
    float w = ew[e];
    unsigned long long fx = (unsigned long long)(w * 1073741824.0f);  // 2^30
    unsigned long long old = atomicAdd(&packed[d], (1ULL << 40) | fx);
    rank[e] = (unsigned short)(old >> 40);
}

__global__ __launch_bounds__(256) void k_dinv(const unsigned long long* __restrict__ packed,
                                              float* __restrict__ dinv) {
    int i = blockIdx.x * 256 + threadIdx.x;
    unsigned long long p = packed[i];
    float deg = 1.0f + (float)(p & ((1ULL << 40) - 1)) * (1.0f / 1073741824.0f);
    dinv[i] = rsqrtf(deg);
}

// block-level inclusive scan -> exclusive per-element, block sums out
__global__ __launch_bounds__(256) void k_scan1(const unsigned long long* __restrict__ packed,
                                               int* __restrict__ row_ptr,
                                               int* __restrict__ bsums) {
    __shared__ int s[256];
    int t = threadIdx.x;
    int i = blockIdx.x * 256 + t;
    int v = (int)(packed[i] >> 40);
    s[t] = v;
    __syncthreads();
    for (int off = 1; off < 256; off <<= 1) {
        int tv = (t >= off) ? s[t - off] : 0;
        __syncthreads();
        s[t] += tv;
        __syncthreads();
    }
    row_ptr[i] = s[t] - v;  // exclusive
    if (t == 255) bsums[blockIdx.x] = s[255];
}

__global__ __launch_bounds__(256) void k_scan2(const int* __restrict__ bsums,
                                               int* __restrict__ boffs) {
    __shared__ int s[256];
    int t = threadIdx.x;
    int v = bsums[t];
    s[t] = v;
    __syncthreads();
    for (int off = 1; off < 256; off <<= 1) {
        int tv = (t >= off) ? s[t - off] : 0;
        __syncthreads();
        s[t] += tv;
        __syncthreads();
    }
    boffs[t] = s[t] - v;  // exclusive
}

__global__ __launch_bounds__(256) void k_scan_add(int* __restrict__ row_ptr,
                                                  const int* __restrict__ boffs) {
    int i = blockIdx.x * 256 + threadIdx.x;
    row_ptr[i] += boffs[blockIdx.x];
    if (i == 0) row_ptr[N_NODES] = N_EDGES;
}

// atomic-free scatter: position comes from rank captured in k_hist
__global__ __launch_bounds__(256) void k_scatter(const int* __restrict__ srcArr,
                                                 const int* __restrict__ dstArr,
                                                 const float* __restrict__ ew,
                                                 const float* __restrict__ dinv,
                                                 const int* __restrict__ row_ptr,
                                                 const unsigned short* __restrict__ rank,
                                                 int* __restrict__ src_perm,
                                                 float* __restrict__ coef_perm) {
    int e = blockIdx.x * 256 + threadIdx.x;
    int s = srcArr[e];
    int d = dstArr[e];
    int j = row_ptr[d] + (int)rank[e];
    src_perm[j] = s;
    coef_perm[j] = dinv[s] * ew[e] * dinv[d];
}

// ---------------- fp32 GEMM: C[N x BN] = X[N x 128] @ W[128 x BN] ----------------
// BM=128, BK=32, 256 threads, thread tile 8 x (BN/16).
// OUTH: store output as fp16 (halves store traffic + downstream gather bytes).

template <int BN, bool BIAS, bool OUTH>
__global__ __launch_bounds__(256) void k_gemm(const float* __restrict__ X,
                                              const float* __restrict__ W,
                                              const float* __restrict__ bias,
                                              void* __restrict__ Cout) {
    constexpr int TN = BN / 16;
    __shared__ float Xs[32][132];      // [k][row], padded
    __shared__ float Ws[32][BN + 4];   // [k][col], padded

    const int tid = threadIdx.x;
    const int tr = tid >> 4;   // rows tr*8 .. tr*8+7
    const int tc = tid & 15;   // cols tc*TN .. tc*TN+TN-1
    const long rowbase = (long)blockIdx.x * 128;

    float acc[8][TN];
#pragma unroll
    for (int i = 0; i < 8; ++i)
#pragma unroll
        for (int j = 0; j < TN; ++j) acc[i][j] = 0.f;

    for (int kk = 0; kk < 128; kk += 32) {
#pragma unroll
        for (int t = 0; t < 4; ++t) {
            int q = tid + t * 256;  // 0..1023 float4s
            int row = q >> 3;
            int c4 = q & 7;
            float4 v = *(const float4*)&X[(rowbase + row) * 128 + kk + c4 * 4];
            Xs[c4 * 4 + 0][row] = v.x;
            Xs[c4 * 4 + 1][row] = v.y;
            Xs[c4 * 4 + 2][row] = v.z;
            Xs[c4 * 4 + 3][row] = v.w;
        }
#pragma unroll
        for (int t = 0; t < (32 * BN / 4) / 256; ++t) {
            int q = tid + t * 256;
            int row = q / (BN / 4);
            int c4 = q % (BN / 4);
            *(float4*)&Ws[row][c4 * 4] = *(const float4*)&W[(kk + row) * BN + c4 * 4];
        }
        __syncthreads();

#pragma unroll 8
        for (int k = 0; k < 32; ++k) {
            float a[8], b[TN];
            *(float4*)&a[0] = *(const float4*)&Xs[k][tr * 8];
            *(float4*)&a[4] = *(const float4*)&Xs[k][tr * 8 + 4];
#pragma unroll
            for (int j = 0; j < TN; j += 4)
                *(float4*)&b[j] = *(const float4*)&Ws[k][tc * TN + j];
#pragma unroll
            for (int i = 0; i < 8; ++i)
#pragma unroll
                for (int j = 0; j < TN; ++j)
                    acc[i][j] = fmaf(a[i], b[j], acc[i][j]);
        }
        __syncthreads();
    }

#pragma unroll
    for (int i = 0; i < 8; ++i) {
        long row = rowbase + tr * 8 + i;
        if (OUTH) {
            __half hb[TN];
#pragma unroll
            for (int j = 0; j < TN; ++j) {
                float v = acc[i][j];
                if (BIAS) v += bias[tc * TN + j];
                hb[j] = __float2half(v);
            }
            // TN=8 -> 16B aligned store
            *(float4*)&((__half*)Cout)[row * BN + tc * TN] = *(float4*)hb;
        } else {
#pragma unroll
            for (int j = 0; j < TN; j += 4) {
                float4 v;
                v.x = acc[i][j];
                v.y = acc[i][j + 1];
                v.z = acc[i][j + 2];
                v.w = acc[i][j + 3];
                if (BIAS) {
                    v.x += bias[tc * TN + j];
                    v.y += bias[tc * TN + j + 1];
                    v.z += bias[tc * TN + j + 2];
                    v.w += bias[tc * TN + j + 3];
                }
                *(float4*)&((float*)Cout)[row * BN + tc * TN + j] = v;
            }
        }
    }
}

// ---------------- CSR gather aggregation (fp16 h) ----------------
// one wave per dst node; 64 lanes x half2 = 128 features (256 B/row).
// Batch-load 64 (src,coef) pairs coalesced, shfl-broadcast, 8 independent
// row-gathers in flight into 8 accumulators. Tail coef=0 -> row 0 (harmless).

__global__ __launch_bounds__(256) void k_aggregate(const __half2* __restrict__ hlin,
                                                   const int* __restrict__ row_ptr,
                                                   const int* __restrict__ src_perm,
                                                   const float* __restrict__ coef,
                                                   const float* __restrict__ dinv,
                                                   const float* __restrict__ bias,
                                                   float* __restrict__ out,
                                                   int do_relu) {
    int wave = threadIdx.x >> 6;
    int lane = threadIdx.x & 63;
    int n = (blockIdx.x << 2) + wave;

    float di = dinv[n];
    float sc = di * di;

    float2 h0 = __half22float2(hlin[(size_t)n * 64 + lane]);
    float2 a0, a1, a2, a3, a4, a5, a6, a7;
    a0.x = h0.x * sc; a0.y = h0.y * sc;
    a1 = a2 = a3 = a4 = a5 = a6 = a7 = make_float2(0.f, 0.f);

    int beg = row_ptr[n];
    int end = row_ptr[n + 1];
    for (int jb = beg; jb < end; jb += 64) {
        int nload = end - jb;
        if (nload > 64) nload = 64;
        int s = 0;
        float c = 0.f;
        if (lane < nload) {
            s = src_perm[jb + lane];
            c = coef[jb + lane];
        }
        for (int q = 0; q < nload; q += 8) {
            int s0 = __shfl(s, q + 0), s1 = __shfl(s, q + 1);
            int s2 = __shfl(s, q + 2), s3 = __shfl(s, q + 3);
            int s4 = __shfl(s, q + 4), s5 = __shfl(s, q + 5);
            int s6 = __shfl(s, q + 6), s7 = __shfl(s, q + 7);
            float c0 = __shfl(c, q + 0), c1 = __shfl(c, q + 1);
            float c2 = __shfl(c, q + 2), c3 = __shfl(c, q + 3);
            float c4 = __shfl(c, q + 4), c5 = __shfl(c, q + 5);
            float c6 = __shfl(c, q + 6), c7 = __shfl(c, q + 7);
            __half2 g0 = hlin[(size_t)s0 * 64 + lane];
            __half2 g1 = hlin[(size_t)s1 * 64 + lane];
            __half2 g2 = hlin[(size_t)s2 * 64 + lane];
            __half2 g3 = hlin[(size_t)s3 * 64 + lane];
            __half2 g4 = hlin[(size_t)s4 * 64 + lane];
            __half2 g5 = hlin[(size_t)s5 * 64 + lane];
            __half2 g6 = hlin[(size_t)s6 * 64 + lane];
            __half2 g7 = hlin[(size_t)s7 * 64 + lane];
            float2 f0 = __half22float2(g0), f1 = __half22float2(g1);
            float2 f2 = __half22float2(g2), f3 = __half22float2(g3);
            float2 f4 = __half22float2(g4), f5 = __half22float2(g5);
            float2 f6 = __half22float2(g6), f7 = __half22float2(g7);
            a0.x = fmaf(c0, f0.x, a0.x); a0.y = fmaf(c0, f0.y, a0.y);
            a1.x = fmaf(c1, f1.x, a1.x); a1.y = fmaf(c1, f1.y, a1.y);
            a2.x = fmaf(c2, f2.x, a2.x); a2.y = fmaf(c2, f2.y, a2.y);
            a3.x = fmaf(c3, f3.x, a3.x); a3.y = fmaf(c3, f3.y, a3.y);
            a4.x = fmaf(c4, f4.x, a4.x); a4.y = fmaf(c4, f4.y, a4.y);
            a5.x = fmaf(c5, f5.x, a5.x); a5.y = fmaf(c5, f5.y, a5.y);
            a6.x = fmaf(c6, f6.x, a6.x); a6.y = fmaf(c6, f6.y, a6.y);
            a7.x = fmaf(c7, f7.x, a7.x); a7.y = fmaf(c7, f7.y, a7.y);
        }
    }

    float2 acc;
    acc.x = ((a0.x + a1.x) + (a2.x + a3.x)) + ((a4.x + a5.x) + (a6.x + a7.x));
    acc.y = ((a0.y + a1.y) + (a2.y + a3.y)) + ((a4.y + a5.y) + (a6.y + a7.y));

    float2 bb = ((const float2*)bias)[lane];
    acc.x += bb.x;
    acc.y += bb.y;
    if (do_relu) {
        acc.x = fmaxf(acc.x, 0.f);
        acc.y = fmaxf(acc.y, 0.f);
    }
    ((float2*)out)[(size_t)n * 64 + lane] = acc;
}

// ---------------- launch ----------------

extern "C" void kernel_launch(void* const* d_in, const int* in_sizes, int n_in,
                              void* d_out, int out_size, void* d_ws, size_t ws_size,
                              hipStream_t stream) {
    const float* x   = (const float*)d_in[0];
    const int*   ei  = (const int*)d_in[1];
    const float* ew  = (const float*)d_in[2];
    const float* W1  = (const float*)d_in[4];
    const float* b1  = (const float*)d_in[5];
    const float* W2  = (const float*)d_in[6];
    const float* b2  = (const float*)d_in[7];
    const float* fcW = (const float*)d_in[8];
    const float* fcb = (const float*)d_in[9];
    float* out = (float*)d_out;

    const int* srcArr = ei;             // edge_index[0]
    const int* dstArr = ei + N_EDGES;   // edge_index[1]

    char* w = (char*)d_ws;
    unsigned long long* packed = (unsigned long long*)w; w += (size_t)N_NODES * 8;
    float* dinv = (float*)w;           w += (size_t)N_NODES * 4;
    unsigned short* rank = (unsigned short*)w; w += (size_t)N_EDGES * 2;
    int* row_ptr = (int*)w;            w += (size_t)(N_NODES + 64) * 4;
    int* bsums = (int*)w;              w += 256 * 4;
    int* boffs = (int*)w;              w += 256 * 4;
    int* src_perm = (int*)w;           w += (size_t)N_EDGES * 4;
    float* coef = (float*)w;           w += (size_t)N_EDGES * 4;
    __half2* bufH = (__half2*)w;       w += (size_t)N_NODES * F * 2;  // fp16 h
    float* bufB = (float*)w;           w += (size_t)N_NODES * F * 4;  // fp32 agg out

    k_zero<<<N_NODES / 256, 256, 0, stream>>>(packed);
    k_hist<<<N_EDGES / 256, 256, 0, stream>>>(dstArr, ew, packed, rank);
    k_dinv<<<N_NODES / 256, 256, 0, stream>>>(packed, dinv);
    k_scan1<<<256, 256, 0, stream>>>(packed, row_ptr, bsums);
    k_scan2<<<1, 256, 0, stream>>>(bsums, boffs);
    k_scan_add<<<256, 256, 0, stream>>>(row_ptr, boffs);
    k_scatter<<<N_EDGES / 256, 256, 0, stream>>>(srcArr, dstArr, ew, dinv, row_ptr, rank,
                                                 src_perm, coef);

    // layer 1: h1 (fp16) = x @ W1 ; agg -> bufB (fp32, relu)
    k_gemm<128, false, true><<<512, 256, 0, stream>>>(x, W1, nullptr, bufH);
    k_aggregate<<<N_NODES / 4, 256, 0, stream>>>(bufH, row_ptr, src_perm, coef, dinv, b1,
                                                 bufB, 1);
    // layer 2: h2 (fp16) = bufB @ W2 ; agg -> bufB (overwrite ok, serial)
    k_gemm<128, false, true><<<512, 256, 0, stream>>>(bufB, W2, nullptr, bufH);
    k_aggregate<<<N_NODES / 4, 256, 0, stream>>>(bufH, row_ptr, src_perm, coef, dinv, b2,
                                                 bufB, 1);
    // FC: out (fp32) = bufB @ fcW + fcb
    k_gemm<64, true, false><<<512, 256, 0, stream>>>(bufB, fcW, fcb, out);
}

// Round 5
// 242.221 us; speedup vs baseline: 1.9527x; 1.0618x over previous
//
#include <hip/hip_runtime.h>
#include <hip/hip_fp16.h>

#define N_NODES 65536
#define N_EDGES 1048576
#define F 128
#define NBUCK 256          // dst >> 8 ; 256 nodes per bucket, ~4096 edges per bucket

typedef unsigned long long ull;

// ---------------- bucket partition (LDS-staged, kills atomic+scatter cost) ----

__global__ __launch_bounds__(256) void k_zero256(int* gcnt) {
    gcnt[threadIdx.x] = 0;
}

// pass A: count edges per coarse bucket
__global__ __launch_bounds__(256) void k_bcount(const int* __restrict__ dst,
                                                int* __restrict__ gcnt) {
    __shared__ int hist[NBUCK];
    int t = threadIdx.x;
    hist[t] = 0;
    __syncthreads();
    int base = blockIdx.x * 4096;
#pragma unroll
    for (int i = 0; i < 16; ++i) {
        int d = dst[base + i * 256 + t];
        atomicAdd(&hist[d >> 8], 1);
    }
    __syncthreads();
    atomicAdd(&gcnt[t], hist[t]);
}

// scan 256 bucket counts -> boff[257] and working fill cursors gfill[256]
__global__ __launch_bounds__(256) void k_bscan(const int* __restrict__ gcnt,
                                               int* __restrict__ boff,
                                               int* __restrict__ gfill) {
    __shared__ int s[256];
    int t = threadIdx.x;
    int v = gcnt[t];
    s[t] = v;
    __syncthreads();
    for (int off = 1; off < 256; off <<= 1) {
        int tv = (t >= off) ? s[t - off] : 0;
        __syncthreads();
        s[t] += tv;
        __syncthreads();
    }
    int excl = s[t] - v;
    boff[t] = excl;
    gfill[t] = excl;
    if (t == 255) boff[256] = N_EDGES;
}

// pass B: partition edges into bucket-contiguous packed records
// brec: ew(32) | dloc(8 @ bit16) | src(16)
__global__ __launch_bounds__(256) void k_bpart(const int* __restrict__ srcArr,
                                               const int* __restrict__ dstArr,
                                               const float* __restrict__ ew,
                                               int* __restrict__ gfill,
                                               ull* __restrict__ brec) {
    __shared__ int hist[NBUCK];
    __shared__ int cur[NBUCK];
    int t = threadIdx.x;
    hist[t] = 0;
    __syncthreads();
    int base = blockIdx.x * 4096;
    int dv[16];
#pragma unroll
    for (int i = 0; i < 16; ++i) {
        dv[i] = dstArr[base + i * 256 + t];
        atomicAdd(&hist[dv[i] >> 8], 1);
    }
    __syncthreads();
    cur[t] = atomicAdd(&gfill[t], hist[t]);
    __syncthreads();
#pragma unroll
    for (int i = 0; i < 16; ++i) {
        int e = base + i * 256 + t;
        int d = dv[i];
        unsigned int s = (unsigned int)srcArr[e];
        unsigned int wb = __float_as_uint(ew[e]);
        int pos = atomicAdd(&cur[d >> 8], 1);
        brec[pos] = ((ull)wb << 32) | ((ull)(d & 255) << 16) | (ull)s;
    }
}

// per-bucket CSR build: LDS hist (count<<40 | fixedpoint ew-sum), dinv,
// local scan -> row_ptr, LDS-cursor rank -> edge8 = ew(32)|src(16)
__global__ __launch_bounds__(256) void k_build(const ull* __restrict__ brec,
                                               const int* __restrict__ boff,
                                               float* __restrict__ dinv,
                                               int* __restrict__ row_ptr,
                                               ull* __restrict__ edge8) {
    __shared__ ull packed[256];
    __shared__ int sc[256];
    __shared__ int cur[256];
    int t = threadIdx.x;
    int b = blockIdx.x;
    packed[t] = 0ULL;
    __syncthreads();

    int beg = boff[b], end = boff[b + 1];
    for (int j = beg + t; j < end; j += 256) {
        ull r = brec[j];
        int dloc = (int)((r >> 16) & 255);
        float w = __uint_as_float((unsigned int)(r >> 32));
        ull fx = (ull)(w * 1073741824.0f);  // 2^30 fixed point (exact match to prior)
        atomicAdd(&packed[dloc], (1ULL << 40) | fx);
    }
    __syncthreads();

    ull p = packed[t];
    int c = (int)(p >> 40);
    float deg = 1.0f + (float)(p & ((1ULL << 40) - 1)) * (1.0f / 1073741824.0f);
    dinv[b * 256 + t] = rsqrtf(deg);

    // exclusive scan of counts
    sc[t] = c;
    __syncthreads();
    for (int off = 1; off < 256; off <<= 1) {
        int tv = (t >= off) ? sc[t - off] : 0;
        __syncthreads();
        sc[t] += tv;
        __syncthreads();
    }
    int excl = sc[t] - c;
    row_ptr[b * 256 + t] = beg + excl;
    if (b == 255 && t == 255) row_ptr[N_NODES] = N_EDGES;
    cur[t] = beg + excl;
    __syncthreads();

    for (int j = beg + t; j < end; j += 256) {
        ull r = brec[j];
        int dloc = (int)((r >> 16) & 255);
        int pos = atomicAdd(&cur[dloc], 1);
        edge8[pos] = (r & 0xFFFFFFFF00000000ULL) | (r & 0xFFFFULL);  // ew | src
    }
}

// coef' = dinv[src] * ew  (dinv[dst] factor folded into aggregate epilogue)
__global__ __launch_bounds__(256) void k_coef(ull* __restrict__ edge8,
                                              const float* __restrict__ dinv) {
    int e0 = (blockIdx.x * 256 + threadIdx.x) * 4;
#pragma unroll
    for (int i = 0; i < 4; ++i) {
        int e = e0 + i;
        ull r = edge8[e];
        int s = (int)(r & 0xFFFF);
        float w = __uint_as_float((unsigned int)(r >> 32));
        float c = dinv[s] * w;
        edge8[e] = ((ull)__float_as_uint(c) << 32) | (r & 0xFFFFULL);
    }
}

// ---------------- fp32 GEMM: C[N x BN] = X[N x 128] @ W[128 x BN] ----------------

template <int BN, bool BIAS, bool OUTH>
__global__ __launch_bounds__(256) void k_gemm(const float* __restrict__ X,
                                              const float* __restrict__ W,
                                              const float* __restrict__ bias,
                                              void* __restrict__ Cout) {
    constexpr int TN = BN / 16;
    __shared__ float Xs[32][132];
    __shared__ float Ws[32][BN + 4];

    const int tid = threadIdx.x;
    const int tr = tid >> 4;
    const int tc = tid & 15;
    const long rowbase = (long)blockIdx.x * 128;

    float acc[8][TN];
#pragma unroll
    for (int i = 0; i < 8; ++i)
#pragma unroll
        for (int j = 0; j < TN; ++j) acc[i][j] = 0.f;

    for (int kk = 0; kk < 128; kk += 32) {
#pragma unroll
        for (int t = 0; t < 4; ++t) {
            int q = tid + t * 256;
            int row = q >> 3;
            int c4 = q & 7;
            float4 v = *(const float4*)&X[(rowbase + row) * 128 + kk + c4 * 4];
            Xs[c4 * 4 + 0][row] = v.x;
            Xs[c4 * 4 + 1][row] = v.y;
            Xs[c4 * 4 + 2][row] = v.z;
            Xs[c4 * 4 + 3][row] = v.w;
        }
#pragma unroll
        for (int t = 0; t < (32 * BN / 4) / 256; ++t) {
            int q = tid + t * 256;
            int row = q / (BN / 4);
            int c4 = q % (BN / 4);
            *(float4*)&Ws[row][c4 * 4] = *(const float4*)&W[(kk + row) * BN + c4 * 4];
        }
        __syncthreads();

#pragma unroll 8
        for (int k = 0; k < 32; ++k) {
            float a[8], b[TN];
            *(float4*)&a[0] = *(const float4*)&Xs[k][tr * 8];
            *(float4*)&a[4] = *(const float4*)&Xs[k][tr * 8 + 4];
#pragma unroll
            for (int j = 0; j < TN; j += 4)
                *(float4*)&b[j] = *(const float4*)&Ws[k][tc * TN + j];
#pragma unroll
            for (int i = 0; i < 8; ++i)
#pragma unroll
                for (int j = 0; j < TN; ++j)
                    acc[i][j] = fmaf(a[i], b[j], acc[i][j]);
        }
        __syncthreads();
    }

#pragma unroll
    for (int i = 0; i < 8; ++i) {
        long row = rowbase + tr * 8 + i;
        if (OUTH) {
            __half hb[TN];
#pragma unroll
            for (int j = 0; j < TN; ++j) {
                float v = acc[i][j];
                if (BIAS) v += bias[tc * TN + j];
                hb[j] = __float2half(v);
            }
            *(float4*)&((__half*)Cout)[row * BN + tc * TN] = *(float4*)hb;
        } else {
#pragma unroll
            for (int j = 0; j < TN; j += 4) {
                float4 v;
                v.x = acc[i][j];
                v.y = acc[i][j + 1];
                v.z = acc[i][j + 2];
                v.w = acc[i][j + 3];
                if (BIAS) {
                    v.x += bias[tc * TN + j];
                    v.y += bias[tc * TN + j + 1];
                    v.z += bias[tc * TN + j + 2];
                    v.w += bias[tc * TN + j + 3];
                }
                *(float4*)&((float*)Cout)[row * BN + tc * TN + j] = v;
            }
        }
    }
}

// ---------------- CSR gather aggregation (fp16 h, packed 8B edges) ----------------
// out[n] = relu( di*Sum_j coef'_j h[src_j] + di^2 h[n] + b )

__global__ __launch_bounds__(256) void k_aggregate(const __half2* __restrict__ hlin,
                                                   const int* __restrict__ row_ptr,
                                                   const ull* __restrict__ edge8,
                                                   const float* __restrict__ dinv,
                                                   const float* __restrict__ bias,
                                                   float* __restrict__ out,
                                                   int do_relu) {
    int wave = threadIdx.x >> 6;
    int lane = threadIdx.x & 63;
    int n = (blockIdx.x << 2) + wave;

    float di = dinv[n];
    float sc = di * di;

    float2 h0 = __half22float2(hlin[(size_t)n * 64 + lane]);
    float2 a0, a1, a2, a3, a4, a5, a6, a7;
    a0 = a1 = a2 = a3 = a4 = a5 = a6 = a7 = make_float2(0.f, 0.f);

    int beg = row_ptr[n];
    int end = row_ptr[n + 1];
    for (int jb = beg; jb < end; jb += 64) {
        int nload = end - jb;
        if (nload > 64) nload = 64;
        ull r = 0ULL;
        if (lane < nload) r = edge8[jb + lane];
        for (int q = 0; q < nload; q += 8) {
            ull r0 = __shfl(r, q + 0), r1 = __shfl(r, q + 1);
            ull r2 = __shfl(r, q + 2), r3 = __shfl(r, q + 3);
            ull r4 = __shfl(r, q + 4), r5 = __shfl(r, q + 5);
            ull r6 = __shfl(r, q + 6), r7 = __shfl(r, q + 7);
            int s0 = (int)(r0 & 0xFFFF), s1 = (int)(r1 & 0xFFFF);
            int s2 = (int)(r2 & 0xFFFF), s3 = (int)(r3 & 0xFFFF);
            int s4 = (int)(r4 & 0xFFFF), s5 = (int)(r5 & 0xFFFF);
            int s6 = (int)(r6 & 0xFFFF), s7 = (int)(r7 & 0xFFFF);
            float c0 = __uint_as_float((unsigned int)(r0 >> 32));
            float c1 = __uint_as_float((unsigned int)(r1 >> 32));
            float c2 = __uint_as_float((unsigned int)(r2 >> 32));
            float c3 = __uint_as_float((unsigned int)(r3 >> 32));
            float c4 = __uint_as_float((unsigned int)(r4 >> 32));
            float c5 = __uint_as_float((unsigned int)(r5 >> 32));
            float c6 = __uint_as_float((unsigned int)(r6 >> 32));
            float c7 = __uint_as_float((unsigned int)(r7 >> 32));
            __half2 g0 = hlin[(size_t)s0 * 64 + lane];
            __half2 g1 = hlin[(size_t)s1 * 64 + lane];
            __half2 g2 = hlin[(size_t)s2 * 64 + lane];
            __half2 g3 = hlin[(size_t)s3 * 64 + lane];
            __half2 g4 = hlin[(size_t)s4 * 64 + lane];
            __half2 g5 = hlin[(size_t)s5 * 64 + lane];
            __half2 g6 = hlin[(size_t)s6 * 64 + lane];
            __half2 g7 = hlin[(size_t)s7 * 64 + lane];
            float2 f0 = __half22float2(g0), f1 = __half22float2(g1);
            float2 f2 = __half22float2(g2), f3 = __half22float2(g3);
            float2 f4 = __half22float2(g4), f5 = __half22float2(g5);
            float2 f6 = __half22float2(g6), f7 = __half22float2(g7);
            a0.x = fmaf(c0, f0.x, a0.x); a0.y = fmaf(c0, f0.y, a0.y);
            a1.x = fmaf(c1, f1.x, a1.x); a1.y = fmaf(c1, f1.y, a1.y);
            a2.x = fmaf(c2, f2.x, a2.x); a2.y = fmaf(c2, f2.y, a2.y);
            a3.x = fmaf(c3, f3.x, a3.x); a3.y = fmaf(c3, f3.y, a3.y);
            a4.x = fmaf(c4, f4.x, a4.x); a4.y = fmaf(c4, f4.y, a4.y);
            a5.x = fmaf(c5, f5.x, a5.x); a5.y = fmaf(c5, f5.y, a5.y);
            a6.x = fmaf(c6, f6.x, a6.x); a6.y = fmaf(c6, f6.y, a6.y);
            a7.x = fmaf(c7, f7.x, a7.x); a7.y = fmaf(c7, f7.y, a7.y);
        }
    }

    float2 sum;
    sum.x = ((a0.x + a1.x) + (a2.x + a3.x)) + ((a4.x + a5.x) + (a6.x + a7.x));
    sum.y = ((a0.y + a1.y) + (a2.y + a3.y)) + ((a4.y + a5.y) + (a6.y + a7.y));

    float2 bb = ((const float2*)bias)[lane];
    float2 acc;
    acc.x = fmaf(di, sum.x, fmaf(sc, h0.x, bb.x));
    acc.y = fmaf(di, sum.y, fmaf(sc, h0.y, bb.y));
    if (do_relu) {
        acc.x = fmaxf(acc.x, 0.f);
        acc.y = fmaxf(acc.y, 0.f);
    }
    ((float2*)out)[(size_t)n * 64 + lane] = acc;
}

// ---------------- launch ----------------

extern "C" void kernel_launch(void* const* d_in, const int* in_sizes, int n_in,
                              void* d_out, int out_size, void* d_ws, size_t ws_size,
                              hipStream_t stream) {
    const float* x   = (const float*)d_in[0];
    const int*   ei  = (const int*)d_in[1];
    const float* ew  = (const float*)d_in[2];
    const float* W1  = (const float*)d_in[4];
    const float* b1  = (const float*)d_in[5];
    const float* W2  = (const float*)d_in[6];
    const float* b2  = (const float*)d_in[7];
    const float* fcW = (const float*)d_in[8];
    const float* fcb = (const float*)d_in[9];
    float* out = (float*)d_out;

    const int* srcArr = ei;             // edge_index[0]
    const int* dstArr = ei + N_EDGES;   // edge_index[1]

    char* w = (char*)d_ws;
    int* gcnt = (int*)w;               w += 256 * 4;
    int* boff = (int*)w;               w += 257 * 4;
    int* gfill = (int*)w;              w += 256 * 4;
    w += 4;                            // align
    float* dinv = (float*)w;           w += (size_t)N_NODES * 4;
    int* row_ptr = (int*)w;            w += (size_t)(N_NODES + 64) * 4;
    ull* edge8 = (ull*)w;              w += (size_t)N_EDGES * 8;
    __half2* bufH = (__half2*)w;       w += (size_t)N_NODES * F * 2;  // 16MB
    float* bufB = (float*)w;           w += (size_t)N_NODES * F * 4;  // 32MB
    ull* brec = (ull*)bufH;            // 8MB, dead before gemm1 writes bufH

    k_zero256<<<1, 256, 0, stream>>>(gcnt);
    k_bcount<<<N_EDGES / 4096, 256, 0, stream>>>(dstArr, gcnt);
    k_bscan<<<1, 256, 0, stream>>>(gcnt, boff, gfill);
    k_bpart<<<N_EDGES / 4096, 256, 0, stream>>>(srcArr, dstArr, ew, gfill, brec);
    k_build<<<NBUCK, 256, 0, stream>>>(brec, boff, dinv, row_ptr, edge8);
    k_coef<<<N_EDGES / 1024, 256, 0, stream>>>(edge8, dinv);

    // layer 1: h1 (fp16) = x @ W1 ; agg -> bufB (fp32, relu)
    k_gemm<128, false, true><<<512, 256, 0, stream>>>(x, W1, nullptr, bufH);
    k_aggregate<<<N_NODES / 4, 256, 0, stream>>>(bufH, row_ptr, edge8, dinv, b1, bufB, 1);
    // layer 2
    k_gemm<128, false, true><<<512, 256, 0, stream>>>(bufB, W2, nullptr, bufH);
    k_aggregate<<<N_NODES / 4, 256, 0, stream>>>(bufH, row_ptr, edge8, dinv, b2, bufB, 1);
    // FC
    k_gemm<64, true, false><<<512, 256, 0, stream>>>(bufB, fcW, fcb, out);
}